// Round 4
// baseline (420.335 us; speedup 1.0000x reference)
//
#include <hip/hip_runtime.h>

#define N_NODES 50000
#define N_EDGES 800000
#define SCAN_BLOCKS 196          // ceil(50000/256)
#define WIN 6250                 // dst window per XCD group (50000/8)
#define PLANE 1600000            // 50000*32 elements per dim-plane
#define AGG_B 120                // blocks per role in segmented agg
#define GHALF (AGG_B * 64)       // groups per node-half (120*4 waves*16 groups)

typedef __attribute__((ext_vector_type(8))) short short8;
typedef __attribute__((ext_vector_type(4))) float f32x4;
typedef unsigned short ushort_t;
typedef unsigned int uint_t;

// ---------------- helpers ----------------
__device__ inline ushort_t f2bf(float f) {
    union { float f; uint_t u; } v; v.f = f;
    uint_t u = v.u;
    u += 0x7fffu + ((u >> 16) & 1u);   // RNE
    return (ushort_t)(u >> 16);
}
__device__ inline float bflo(uint_t v) { return __uint_as_float(v << 16); }
__device__ inline float bfhi(uint_t v) { return __uint_as_float(v & 0xffff0000u); }

#define ACC8(V) { a[0] += bflo((V).x); a[1] += bfhi((V).x); \
                  a[2] += bflo((V).y); a[3] += bfhi((V).y); \
                  a[4] += bflo((V).z); a[5] += bfhi((V).z); \
                  a[6] += bflo((V).w); a[7] += bfhi((V).w); }

// ---------------- CSR build: XCD-windowed counting sort ----------------
__global__ void count_edges_mp(const int* __restrict__ ei, int* __restrict__ cnt) {
    int g = blockIdx.x & 7;
    int nb = gridDim.x >> 3;
    int bi = blockIdx.x >> 3;
    int lo = g * WIN;
    for (int e = bi * 256 + threadIdx.x; e < N_EDGES; e += nb * 256) {
        int d = ei[N_EDGES + e];
        if ((unsigned)(d - lo) < WIN) atomicAdd(&cnt[d], 1);
    }
}

__global__ void fill_csr_mp(const int* __restrict__ ei, int* __restrict__ cursor,
                            int* __restrict__ csr_src) {
    int g = blockIdx.x & 7;
    int nb = gridDim.x >> 3;
    int bi = blockIdx.x >> 3;
    int lo = g * WIN;
    for (int e = bi * 256 + threadIdx.x; e < N_EDGES; e += nb * 256) {
        int d = ei[N_EDGES + e];
        if ((unsigned)(d - lo) < WIN) {
            int p = atomicAdd(&cursor[d], 1);
            csr_src[p] = ei[e];
        }
    }
}

__global__ void block_sums(const int* __restrict__ cnt, int* __restrict__ bsum) {
    int i = blockIdx.x * 256 + threadIdx.x;
    int v = (i < N_NODES) ? cnt[i] : 0;
    for (int off = 32; off; off >>= 1) v += __shfl_down(v, off, 64);
    __shared__ int s[4];
    if ((threadIdx.x & 63) == 0) s[threadIdx.x >> 6] = v;
    __syncthreads();
    if (threadIdx.x == 0) bsum[blockIdx.x] = s[0] + s[1] + s[2] + s[3];
}

__global__ void scan_bsums(const int* __restrict__ bsum, int* __restrict__ bprefix,
                           int* __restrict__ rowstart) {
    __shared__ int s[256];
    int t = threadIdx.x;
    int v = (t < SCAN_BLOCKS) ? bsum[t] : 0;
    s[t] = v;
    __syncthreads();
    for (int off = 1; off < 256; off <<= 1) {
        int add = (t >= off) ? s[t - off] : 0;
        __syncthreads();
        s[t] += add;
        __syncthreads();
    }
    bprefix[t] = s[t] - v;
    if (t == 0) rowstart[N_NODES] = N_EDGES;
}

__global__ void apply_scan(const int* __restrict__ cnt, const int* __restrict__ bprefix,
                           int* __restrict__ rowstart, int* __restrict__ cursor,
                           float* __restrict__ invd) {
    __shared__ int s[256];
    int t = threadIdx.x;
    int i = blockIdx.x * 256 + t;
    int v = (i < N_NODES) ? cnt[i] : 0;
    s[t] = v;
    __syncthreads();
    for (int off = 1; off < 256; off <<= 1) {
        int add = (t >= off) ? s[t - off] : 0;
        __syncthreads();
        s[t] += add;
        __syncthreads();
    }
    int excl = s[t] - v + bprefix[blockIdx.x];
    if (i < N_NODES) {
        rowstart[i] = excl; cursor[i] = excl;
        invd[i] = 1.0f / fmaxf((float)v, 1.0f);
    }
}

// ---------------- edge-balanced, node-aligned group partition ----------------
// gs[h*(GHALF+1) + g] = first node of group g within half h. Binary search of
// rowstart at edge quantiles -> ~equal edges per 4-lane group, no atomics.
__global__ void part_groups(const int* __restrict__ rowstart, int* __restrict__ gs) {
    int gid = blockIdx.x * 256 + threadIdx.x;
    if (gid >= 2 * (GHALF + 1)) return;
    int h = gid / (GHALF + 1), g = gid % (GHALF + 1);
    int nlo = h * 25000, nhi = nlo + 25000;
    if (g == 0)      { gs[gid] = nlo; return; }
    if (g == GHALF)  { gs[gid] = nhi; return; }
    int base = rowstart[nlo];
    int tot = rowstart[nhi] - base;
    long target = (long)base + (long)g * tot / GHALF;
    int lo = nlo, hi = nhi;          // rowstart[lo] < target <= rowstart[hi]
    while (hi - lo > 1) {
        int mid = (lo + hi) >> 1;
        if ((long)rowstart[mid] >= target) hi = mid; else lo = mid;
    }
    gs[gid] = hi;
}

// ---------------- fp32 -> bf16, plane-major [4][50000][32] ----------------
__global__ void cvt_bf16_pl(const float* __restrict__ in, ushort_t* __restrict__ out) {
    int i = blockIdx.x * 256 + threadIdx.x;     // over 1.6M float4's
    if (i >= 1600000) return;
    int d0 = (i & 31) * 4;
    int node = i >> 5;
    float4 v = ((const float4*)in)[i];
    ushort4 o;
    o.x = f2bf(v.x); o.y = f2bf(v.y); o.z = f2bf(v.z); o.w = f2bf(v.w);
    int p = d0 >> 5, dd = d0 & 31;
    *(ushort4*)(out + ((size_t)p * 50000 + node) * 32 + dd) = o;
}

// ---------------- fused weight pre-pack (all 3 layers, 1 launch) ----------------
__global__ void pack_all(const float* __restrict__ Wl0, const float* __restrict__ Wr0,
                         const float* __restrict__ Wl1, const float* __restrict__ Wr1,
                         const float* __restrict__ Wl2, const float* __restrict__ Wr2,
                         ushort_t* __restrict__ pk0, ushort_t* __restrict__ pk1,
                         ushort_t* __restrict__ pkz) {
    int gi = blockIdx.x * 256 + threadIdx.x;    // 81920 total
    const float* Wl; const float* Wr; ushort_t* dst; int idx; bool zr = false;
    if (gi < 32768)       { Wl = Wl0; Wr = Wr0; dst = pk0; idx = gi; }
    else if (gi < 65536)  { Wl = Wl1; Wr = Wr1; dst = pk1; idx = gi - 32768; }
    else if (gi < 81920)  { Wl = Wl2; Wr = Wr2; dst = pkz; idx = gi - 65536; zr = true; }
    else return;
    int j = idx & 7, l = (idx >> 3) & 63, t = (idx >> 9) & 7, ks = idx >> 12;
    int n = t * 16 + (l & 15);
    int k = ks * 32 + (l >> 4) * 8 + j;
    float w;
    if (zr) w = (n < 64) ? Wl[k * 64 + n] : Wr[k * 64 + (n - 64)];
    else    w = (k < 128) ? Wl[k * 128 + n] : Wr[(k - 128) * 128 + n];
    dst[idx] = f2bf(w);
}

// ---------------- segmented CSR sum-aggregation (plane-sliced, no shfl) ----------------
// role = blockIdx&7 -> XCD; slice s = role>>1 owns L2-resident dim-plane s;
// half = role&1 owns half the dst nodes. Each 4-lane group walks an
// edge-balanced node range: sequential csr stream + one 64B uint4 gather per
// edge, 16 VALU accumulate, divergent-rare flush at node boundary.
// Stores bf16 SUMS; 1/deg is folded into the GEMM (invd scaling of the
// mean-part accumulator) - mathematically identical to mean@Wl.
#define AGG_FLUSH() { \
    uint_t r0, r1, r2, r3; \
    asm("v_cvt_pk_bf16_f32 %0, %1, %2" : "=v"(r0) : "v"(a[0]), "v"(a[1])); \
    asm("v_cvt_pk_bf16_f32 %0, %1, %2" : "=v"(r1) : "v"(a[2]), "v"(a[3])); \
    asm("v_cvt_pk_bf16_f32 %0, %1, %2" : "=v"(r2) : "v"(a[4]), "v"(a[5])); \
    asm("v_cvt_pk_bf16_f32 %0, %1, %2" : "=v"(r3) : "v"(a[6]), "v"(a[7])); \
    uint4 ov; ov.x = r0; ov.y = r1; ov.z = r2; ov.w = r3; \
    ((uint4*)mb)[(size_t)node * 4 + sl] = ov; \
    a[0]=0.f;a[1]=0.f;a[2]=0.f;a[3]=0.f;a[4]=0.f;a[5]=0.f;a[6]=0.f;a[7]=0.f; \
    ++node; sEnd = rowstart[node + 1]; }

__global__ __launch_bounds__(256) void agg_seg(
    const ushort_t* __restrict__ feat_pl,       // [4][50000][32] bf16
    const int* __restrict__ rowstart,
    const int* __restrict__ csr_src,
    const int* __restrict__ gs,
    ushort_t* __restrict__ sum_pl) {            // [4][50000][32] bf16 sums
    int role = blockIdx.x & 7;
    int bi   = blockIdx.x >> 3;
    int s = role >> 1, h = role & 1;
    int lane = threadIdx.x & 63, wave = threadIdx.x >> 6;
    int grp = lane >> 2, sl = lane & 3;
    int gl = (bi * 4 + wave) * 16 + grp;
    const int* gsh = gs + h * (GHALF + 1);
    int n0 = gsh[gl], n1 = gsh[gl + 1];
    if (n0 >= n1) return;
    const uint4* pb = (const uint4*)((const uint_t*)feat_pl + (size_t)s * (PLANE / 2));
    uint_t* mb = (uint_t*)sum_pl + (size_t)s * (PLANE / 2);

    float a[8] = {0.f,0.f,0.f,0.f,0.f,0.f,0.f,0.f};
    int e = rowstart[n0];
    int eEnd = rowstart[n1];
    int node = n0;
    int sEnd = rowstart[n0 + 1];

    for (; e < eEnd; ++e) {
        while (e >= sEnd) { AGG_FLUSH(); }      // rare, masked
        int idx = csr_src[e];
        uint4 v = pb[(size_t)idx * 4 + sl];
        ACC8(v);
    }
    while (node < n1) { AGG_FLUSH(); }          // last node + trailing empties
}

// ---------------- MFMA GEMM, plane in/out, B staged in LDS ----------------
// h = relu(diag(inv) * (sum @ Wl) + root @ Wr + b), plane-major tensors.
__global__ __launch_bounds__(256) void gemm_pl(
    const ushort_t* __restrict__ sum_pl, const ushort_t* __restrict__ root_pl,
    const ushort_t* __restrict__ Bpk, const float* __restrict__ bias,
    const float* __restrict__ invd,
    ushort_t* __restrict__ out_pl) {
    __shared__ ushort_t bsh[32768];             // 64 KB B-pack
    {
        const uint4* src = (const uint4*)Bpk;
        uint4* dst = (uint4*)bsh;
        for (int i = threadIdx.x; i < 4096; i += 256) dst[i] = src[i];
    }
    __syncthreads();

    int lane = threadIdx.x & 63;
    int wave = threadIdx.x >> 6;
    int row16 = lane & 15;
    int quad = lane >> 4;
    int rowBase = blockIdx.x * 64 + wave * 16;
    int arow = min(rowBase + row16, N_NODES - 1);
    const short8* bp = (const short8*)bsh + lane;

    f32x4 acc[8];
    #pragma unroll
    for (int t = 0; t < 8; ++t) { f32x4 z = {0.f, 0.f, 0.f, 0.f}; acc[t] = z; }

    // mean part: sum planes, scaled by invd after the partial accumulation
    #pragma unroll
    for (int ks = 0; ks < 4; ++ks) {
        short8 afrag = *(const short8*)(sum_pl + ((size_t)ks * 50000 + arow) * 32 + quad * 8);
        #pragma unroll
        for (int t = 0; t < 8; ++t) {
            short8 bfrag = bp[(ks * 8 + t) * 64];
            acc[t] = __builtin_amdgcn_mfma_f32_16x16x32_bf16(afrag, bfrag, acc[t], 0, 0, 0);
        }
    }
    {
        float4 iv = *(const float4*)(invd + rowBase + quad * 4);  // in-ws even past N
        #pragma unroll
        for (int t = 0; t < 8; ++t) {
            acc[t][0] *= iv.x; acc[t][1] *= iv.y;
            acc[t][2] *= iv.z; acc[t][3] *= iv.w;
        }
    }
    // root part
    #pragma unroll
    for (int ks = 4; ks < 8; ++ks) {
        short8 afrag = *(const short8*)(root_pl + ((size_t)(ks - 4) * 50000 + arow) * 32 + quad * 8);
        #pragma unroll
        for (int t = 0; t < 8; ++t) {
            short8 bfrag = bp[(ks * 8 + t) * 64];
            acc[t] = __builtin_amdgcn_mfma_f32_16x16x32_bf16(afrag, bfrag, acc[t], 0, 0, 0);
        }
    }

    #pragma unroll
    for (int t = 0; t < 8; ++t) {
        int col = t * 16 + row16;
        float bv = bias[col];
        int pl = col >> 5, dd = col & 31;
        #pragma unroll
        for (int r = 0; r < 4; ++r) {
            int row = rowBase + quad * 4 + r;
            if (row < N_NODES) {
                float v = fmaxf(acc[t][r] + bv, 0.f);
                out_pl[((size_t)pl * 50000 + row) * 32 + dd] = f2bf(v);
            }
        }
    }
}

// ---------------- layer-2 pre-transform: [z | r] = h @ [Wl2 | Wr2], r += b2 ----------------
// z written as 2 L2-resident planes [2][50000][32] for the segmented final gather.
__global__ __launch_bounds__(256) void gemm_zr_pl(
    const ushort_t* __restrict__ h_pl, const ushort_t* __restrict__ Bpk,
    const float* __restrict__ bias,
    ushort_t* __restrict__ z_pl, float* __restrict__ r_f32) {
    __shared__ ushort_t bsh[16384];             // 32 KB B-pack
    {
        const uint4* src = (const uint4*)Bpk;
        uint4* dst = (uint4*)bsh;
        for (int i = threadIdx.x; i < 2048; i += 256) dst[i] = src[i];
    }
    __syncthreads();

    int lane = threadIdx.x & 63;
    int wave = threadIdx.x >> 6;
    int row16 = lane & 15;
    int quad = lane >> 4;
    int rowBase = blockIdx.x * 64 + wave * 16;
    int arow = min(rowBase + row16, N_NODES - 1);
    const short8* bp = (const short8*)bsh + lane;

    f32x4 acc[8];
    #pragma unroll
    for (int t = 0; t < 8; ++t) { f32x4 z = {0.f, 0.f, 0.f, 0.f}; acc[t] = z; }

    #pragma unroll
    for (int ks = 0; ks < 4; ++ks) {
        short8 afrag = *(const short8*)(h_pl + ((size_t)ks * 50000 + arow) * 32 + quad * 8);
        #pragma unroll
        for (int t = 0; t < 8; ++t) {
            short8 bfrag = bp[(ks * 8 + t) * 64];
            acc[t] = __builtin_amdgcn_mfma_f32_16x16x32_bf16(afrag, bfrag, acc[t], 0, 0, 0);
        }
    }

    #pragma unroll
    for (int t = 0; t < 8; ++t) {
        int col = t * 16 + row16;
        #pragma unroll
        for (int r = 0; r < 4; ++r) {
            int row = rowBase + quad * 4 + r;
            if (row < N_NODES) {
                if (col < 64) {
                    z_pl[((size_t)(col >> 5) * 50000 + row) * 32 + (col & 31)] = f2bf(acc[t][r]);
                } else {
                    r_f32[(size_t)row * 64 + (col - 64)] = acc[t][r] + bias[col - 64];
                }
            }
        }
    }
}

// ---------------- segmented final gather: f32 sums of z[src] ----------------
// role = blockIdx&3: s = role>>1 (2 z-planes), h = role&1; same gs partition.
__global__ __launch_bounds__(256) void fin_seg(
    const ushort_t* __restrict__ z_pl,
    const int* __restrict__ rowstart,
    const int* __restrict__ csr_src,
    const int* __restrict__ gs,
    float* __restrict__ fsum) {                 // [2][50000][32] f32
    int role = blockIdx.x & 3;
    int bi   = blockIdx.x >> 2;
    int s = role >> 1, h = role & 1;
    int lane = threadIdx.x & 63, wave = threadIdx.x >> 6;
    int grp = lane >> 2, sl = lane & 3;
    int gl = (bi * 4 + wave) * 16 + grp;
    const int* gsh = gs + h * (GHALF + 1);
    int n0 = gsh[gl], n1 = gsh[gl + 1];
    if (n0 >= n1) return;
    const uint4* pb = (const uint4*)((const uint_t*)z_pl + (size_t)s * (PLANE / 2));
    float* fb = fsum + (size_t)s * PLANE;

    float a[8] = {0.f,0.f,0.f,0.f,0.f,0.f,0.f,0.f};
    int e = rowstart[n0];
    int eEnd = rowstart[n1];
    int node = n0;
    int sEnd = rowstart[n0 + 1];

#define FIN_FLUSH() { \
    *(float4*)(fb + (size_t)node * 32 + sl * 8)     = make_float4(a[0], a[1], a[2], a[3]); \
    *(float4*)(fb + (size_t)node * 32 + sl * 8 + 4) = make_float4(a[4], a[5], a[6], a[7]); \
    a[0]=0.f;a[1]=0.f;a[2]=0.f;a[3]=0.f;a[4]=0.f;a[5]=0.f;a[6]=0.f;a[7]=0.f; \
    ++node; sEnd = rowstart[node + 1]; }

    for (; e < eEnd; ++e) {
        while (e >= sEnd) { FIN_FLUSH(); }
        int idx = csr_src[e];
        uint4 v = pb[(size_t)idx * 4 + sl];
        ACC8(v);
    }
    while (node < n1) { FIN_FLUSH(); }
#undef FIN_FLUSH
}

// ---------------- final streaming softmax: h = fsum*inv + r; log_softmax ----------------
__global__ __launch_bounds__(256) void softmax_fin(
    const float* __restrict__ fsum, const float* __restrict__ r_f32,
    const float* __restrict__ invd, float* __restrict__ out) {
    int node = blockIdx.x * 4 + (threadIdx.x >> 6);
    int d = threadIdx.x & 63;
    if (node >= N_NODES) return;
    float inv = invd[node];
    float sum = fsum[(size_t)(d >> 5) * PLANE + (size_t)node * 32 + (d & 31)];
    float h = sum * inv + r_f32[(size_t)node * 64 + d];

    float mx = h;
    for (int off = 32; off; off >>= 1) mx = fmaxf(mx, __shfl_xor(mx, off, 64));
    float e = expf(h - mx);
    float ssum = e;
    for (int off = 32; off; off >>= 1) ssum += __shfl_xor(ssum, off, 64);
    float lse = mx + logf(ssum);

    out[(size_t)node * 64 + d] = h - lse;
    out[(size_t)N_NODES * 64 + (size_t)node * 64 + d] = h;
}

extern "C" void kernel_launch(void* const* d_in, const int* in_sizes, int n_in,
                              void* d_out, int out_size, void* d_ws, size_t ws_size,
                              hipStream_t stream) {
    const float* x  = (const float*)d_in[0];
    const int* ei   = (const int*)d_in[1];
    const float* Wl0 = (const float*)d_in[2];
    const float* Wr0 = (const float*)d_in[3];
    const float* b0  = (const float*)d_in[4];
    const float* Wl1 = (const float*)d_in[5];
    const float* Wr1 = (const float*)d_in[6];
    const float* b1  = (const float*)d_in[7];
    const float* Wl2 = (const float*)d_in[8];
    const float* Wr2 = (const float*)d_in[9];
    const float* b2  = (const float*)d_in[10];
    float* out = (float*)d_out;

    char* ws = (char*)d_ws;
    int* cnt      = (int*)(ws + 0x000000);
    int* rowstart = (int*)(ws + 0x040000);
    int* cursor   = (int*)(ws + 0x080000);
    int* bsum     = (int*)(ws + 0x0C0000);
    int* bprefix  = (int*)(ws + 0x0C1000);
    int* gs       = (int*)(ws + 0x0C2000);            // 2*(GHALF+1) ints ~ 61 KB
    int* csr_src  = (int*)(ws + 0x100000);            // 3.2 MB
    ushort_t* pk0 = (ushort_t*)(ws + 0x420000);       // 64 KB
    ushort_t* pk1 = (ushort_t*)(ws + 0x440000);       // 64 KB
    ushort_t* pkz = (ushort_t*)(ws + 0x460000);       // 32 KB
    float* invd   = (float*)(ws + 0x480000);          // 200 KB
    ushort_t* x_pl    = (ushort_t*)(ws + 0x0500000);  // 12.8 MB  [4][50000][32]
    ushort_t* sum_pl  = (ushort_t*)(ws + 0x1200000);  // 12.8 MB  bf16 sums
    ushort_t* h_pl    = (ushort_t*)(ws + 0x1F00000);  // 12.8 MB
    ushort_t* h2_pl   = (ushort_t*)(ws + 0x2C00000);  // 12.8 MB
    ushort_t* z_pl    = (ushort_t*)(ws + 0x3900000);  // 6.4 MB  [2][50000][32]
    float*    r_f32   = (float*)  (ws + 0x4000000);   // 12.8 MB
    float*    fsum    = (float*)  (ws + 0x4D00000);   // 12.8 MB [2][50000][32] f32

    // ---- weight pre-pack (overlaps CSR build) ----
    pack_all<<<320, 256, 0, stream>>>(Wl0, Wr0, Wl1, Wr1, Wl2, Wr2, pk0, pk1, pkz);

    // ---- CSR build (XCD-windowed counting sort) ----
    hipMemsetAsync(cnt, 0, N_NODES * sizeof(int), stream);
    count_edges_mp<<<1024, 256, 0, stream>>>(ei, cnt);
    block_sums<<<SCAN_BLOCKS, 256, 0, stream>>>(cnt, bsum);
    scan_bsums<<<1, 256, 0, stream>>>(bsum, bprefix, rowstart);
    apply_scan<<<SCAN_BLOCKS, 256, 0, stream>>>(cnt, bprefix, rowstart, cursor, invd);
    fill_csr_mp<<<1024, 256, 0, stream>>>(ei, cursor, csr_src);
    part_groups<<<61, 256, 0, stream>>>(rowstart, gs);

    // ---- x -> bf16 planes ----
    cvt_bf16_pl<<<6250, 256, 0, stream>>>(x, x_pl);

    // ---- layer 0 ----
    agg_seg<<<8 * AGG_B, 256, 0, stream>>>(x_pl, rowstart, csr_src, gs, sum_pl);
    gemm_pl<<<782, 256, 0, stream>>>(sum_pl, x_pl, pk0, b0, invd, h_pl);

    // ---- layer 1 ----
    agg_seg<<<8 * AGG_B, 256, 0, stream>>>(h_pl, rowstart, csr_src, gs, sum_pl);
    gemm_pl<<<782, 256, 0, stream>>>(sum_pl, h_pl, pk1, b1, invd, h2_pl);

    // ---- layer 2: transform-first, segmented final gather, streaming softmax ----
    gemm_zr_pl<<<782, 256, 0, stream>>>(h2_pl, pkz, b2, z_pl, r_f32);
    fin_seg<<<4 * AGG_B, 256, 0, stream>>>(z_pl, rowstart, csr_src, gs, fsum);
    softmax_fin<<<12500, 256, 0, stream>>>(fsum, r_f32, invd, out);
}